// Round 1
// baseline (272.645 us; speedup 1.0000x reference)
//
#include <hip/hip_runtime.h>
#include <hip/hip_bf16.h>
#include <stdint.h>

#define N_ROWS 8192
#define D_DIM  1024
#define INV_T  10.0f
#define NEG_BIG -1e30f
#define CHUNK_COLS 2048
#define N_CHUNKS 4
#define NTILES (CHUNK_COLS / 16)

typedef __attribute__((ext_vector_type(8))) short bf16x8;
typedef __attribute__((ext_vector_type(4))) float f32x4;

static __device__ inline unsigned short f2bf(float x) {
    unsigned u = __float_as_uint(x);
    u += 0x7fff + ((u >> 16) & 1);
    return (unsigned short)(u >> 16);
}

// branchless insert of v into descending sorted 5-list b0..b4
#define INS5(b0,b1,b2,b3,b4,v) {            \
    float _x0 = fminf(b0,(v)); b0 = fmaxf(b0,(v));  \
    float _x1 = fminf(b1,_x0); b1 = fmaxf(b1,_x0);  \
    float _x2 = fminf(b2,_x1); b2 = fmaxf(b2,_x1);  \
    float _x3 = fminf(b3,_x2); b3 = fmaxf(b3,_x2);  \
    b4 = fmaxf(b4,_x3); }

// ---------------- K1: row-normalize f32 -> bf16 ----------------
__global__ __launch_bounds__(256) void norm_kernel(const float* __restrict__ z,
                                                   unsigned short* __restrict__ zn) {
    int wave = threadIdx.x >> 6;
    int lane = threadIdx.x & 63;
    int row  = blockIdx.x * 4 + wave;
    const float* zr = z + (size_t)row * D_DIM;
    float4 c[4];
    float ss = 0.f;
#pragma unroll
    for (int i = 0; i < 4; ++i) {
        c[i] = *(const float4*)(zr + i * 256 + lane * 4);
        ss += c[i].x*c[i].x + c[i].y*c[i].y + c[i].z*c[i].z + c[i].w*c[i].w;
    }
#pragma unroll
    for (int m = 1; m < 64; m <<= 1) ss += __shfl_xor(ss, m);
    float scale = 1.0f / fmaxf(sqrtf(ss), 1e-12f);
    unsigned short* zo = zn + (size_t)row * D_DIM;
#pragma unroll
    for (int i = 0; i < 4; ++i) {
        ushort4 o;
        o.x = f2bf(c[i].x * scale);
        o.y = f2bf(c[i].y * scale);
        o.z = f2bf(c[i].z * scale);
        o.w = f2bf(c[i].w * scale);
        *(ushort4*)(zo + i * 256 + lane * 4) = o;
    }
}

// ---------------- K2: fused sim + online LSE + top5 partials ----------------
// grid: 512 blocks = 128 row-groups (64 rows) x 4 column chunks (2048 cols)
// each wave owns 16 rows; A-frags resident in 128 VGPRs; B tile staged in LDS.
__global__ __launch_bounds__(256) void sim_kernel(const unsigned short* __restrict__ zn,
                                                  float* __restrict__ pstats) {
    __shared__ uint4 ldsB[2048];               // 32 KB: 16 rows x 2048 B (swizzled)
    __shared__ float sc_t5[4 * 16 * 16 * 5];   // 20 KB top5 merge scratch
    __shared__ float sc_ms[64 * 2];

    const int tid  = threadIdx.x;
    const int w    = tid >> 6;
    const int lane = tid & 63;
    const int g    = lane >> 4;   // quarter-group (k-offset / acc row-subgroup)
    const int c16  = lane & 15;   // col within 16-tile / A source row

    const int rb    = blockIdx.x & 127;
    const int chunk = blockIdx.x >> 7;

    // A fragments: wave's 16 rows, all of K in registers
    const int row_g = rb * 64 + w * 16 + c16;
    const unsigned short* ar = zn + (size_t)row_g * D_DIM;
    bf16x8 a[32];
#pragma unroll
    for (int kk = 0; kk < 32; ++kk)
        a[kk] = *(const bf16x8*)(ar + kk * 32 + g * 8);

    // per-lane running stats for 4 output rows (acc reg r)
    float sm[4], ssum[4], t5[4][5];
#pragma unroll
    for (int r = 0; r < 4; ++r) {
        sm[r] = NEG_BIG; ssum[r] = 0.f;
#pragma unroll
        for (int k = 0; k < 5; ++k) t5[r][k] = NEG_BIG;
    }
    const int i_base = rb * 64 + w * 16 + g * 4;  // + r = global output row

    for (int t = 0; t < NTILES; ++t) {
        const int j0 = chunk * CHUNK_COLS + t * 16;
        __syncthreads();   // protect ldsB from previous iteration's readers
        {
            // stage B tile: 16 rows (cols j0..j0+15) x 2048 B, XOR-swizzled
            int srow = tid >> 4;            // 0..15
            int sb   = (tid & 15) * 16;     // coalesced 16B per thread
            const uint4* gsrc = (const uint4*)((const char*)zn + (size_t)(j0 + srow) * 2048);
#pragma unroll
            for (int u = 0; u < 8; ++u) {
                int byt = sb + u * 256;
                uint4 v = gsrc[byt >> 4];
                ldsB[(srow * 2048 + (byt ^ ((srow & 7) << 4))) >> 4] = v;
            }
        }
        __syncthreads();

        f32x4 acc = {0.f, 0.f, 0.f, 0.f};
#pragma unroll
        for (int kk = 0; kk < 32; ++kk) {
            int kbyte = kk * 64 + g * 16;
            bf16x8 b = *(const bf16x8*)&ldsB[(c16 * 2048 + (kbyte ^ ((c16 & 7) << 4))) >> 4];
            acc = __builtin_amdgcn_mfma_f32_16x16x32_bf16(a[kk], b, acc, 0, 0, 0);
        }

        const int j = j0 + c16;
#pragma unroll
        for (int r = 0; r < 4; ++r) {
            float v  = acc[r];
            bool ok  = (j != (i_base + r));          // exclude diagonal
            float vm = ok ? v : NEG_BIG;
            INS5(t5[r][0], t5[r][1], t5[r][2], t5[r][3], t5[r][4], vm);
            if (ok) {
                float lgt = v * INV_T;
                float mn  = fmaxf(sm[r], lgt);
                ssum[r] = ssum[r] * __expf(sm[r] - mn) + __expf(lgt - mn);
                sm[r] = mn;
            }
        }
    }

    // merge (m,s) across the 16 lanes of each quarter-group
#pragma unroll
    for (int msk = 1; msk < 16; msk <<= 1) {
#pragma unroll
        for (int r = 0; r < 4; ++r) {
            float mo = __shfl_xor(sm[r], msk);
            float so = __shfl_xor(ssum[r], msk);
            float mn = fmaxf(sm[r], mo);
            ssum[r] = ssum[r] * __expf(sm[r] - mn) + so * __expf(mo - mn);
            sm[r] = mn;
        }
    }
    // dump per-lane top5 + merged (m,s) to LDS
#pragma unroll
    for (int r = 0; r < 4; ++r) {
        int q = g * 4 + r;
        float* dst = &sc_t5[(((w * 16 + q) * 16) + c16) * 5];
#pragma unroll
        for (int k = 0; k < 5; ++k) dst[k] = t5[r][k];
        if (c16 == 0) {
            sc_ms[(w * 16 + q) * 2]     = sm[r];
            sc_ms[(w * 16 + q) * 2 + 1] = ssum[r];
        }
    }
    __syncthreads();

    if (tid < 64) {   // one thread finalizes one of the block's 64 rows
        float M = sc_ms[tid * 2], S = sc_ms[tid * 2 + 1];
        float b0 = NEG_BIG, b1 = NEG_BIG, b2 = NEG_BIG, b3 = NEG_BIG, b4 = NEG_BIG;
        const float* src = &sc_t5[tid * 16 * 5];
        for (int c = 0; c < 80; ++c) { float v = src[c]; INS5(b0,b1,b2,b3,b4,v); }
        int grow = rb * 64 + tid;   // (tid>>4)=wave, (tid&15)=row-in-wave
        float* p = pstats + ((size_t)chunk * N_ROWS + grow) * 8;
        p[0] = M; p[1] = S; p[2] = b0; p[3] = b1; p[4] = b2; p[5] = b3; p[6] = b4;
        p[7] = 0.f;
    }
}

// ---------------- K3: merge partials, compute mean loss ----------------
__global__ __launch_bounds__(256) void reduce_kernel(const float* __restrict__ pstats,
                                                     float* __restrict__ out) {
    __shared__ float red[4];
    float local = 0.f;
    for (int row = threadIdx.x; row < N_ROWS; row += 256) {
        float M = NEG_BIG, S = 0.f;
        float b0 = NEG_BIG, b1 = NEG_BIG, b2 = NEG_BIG, b3 = NEG_BIG, b4 = NEG_BIG;
#pragma unroll
        for (int c = 0; c < N_CHUNKS; ++c) {
            const float* p = pstats + ((size_t)c * N_ROWS + row) * 8;
            float pm = p[0], ps = p[1];
            float mn = fmaxf(M, pm);
            S = S * __expf(M - mn) + ps * __expf(pm - mn);
            M = mn;
#pragma unroll
            for (int k = 0; k < 5; ++k) { float v = p[2 + k]; INS5(b0,b1,b2,b3,b4,v); }
        }
        float S5 = __expf(b0 * INV_T - M) + __expf(b1 * INV_T - M) +
                   __expf(b2 * INV_T - M) + __expf(b3 * INV_T - M) +
                   __expf(b4 * INV_T - M);
        local += __logf(S) - __logf(S5);
    }
#pragma unroll
    for (int m = 1; m < 64; m <<= 1) local += __shfl_xor(local, m);
    if ((threadIdx.x & 63) == 0) red[threadIdx.x >> 6] = local;
    __syncthreads();
    if (threadIdx.x == 0)
        out[0] = (red[0] + red[1] + red[2] + red[3]) * (1.0f / N_ROWS);
}

extern "C" void kernel_launch(void* const* d_in, const int* in_sizes, int n_in,
                              void* d_out, int out_size, void* d_ws, size_t ws_size,
                              hipStream_t stream) {
    const float* z = (const float*)d_in[0];
    float* out = (float*)d_out;
    unsigned short* zn = (unsigned short*)d_ws;                       // 16 MB bf16
    float* pstats = (float*)((char*)d_ws + (size_t)N_ROWS * D_DIM * 2); // 1 MB

    norm_kernel<<<N_ROWS / 4, 256, 0, stream>>>(z, zn);
    sim_kernel<<<128 * N_CHUNKS, 256, 0, stream>>>(zn, pstats);
    reduce_kernel<<<1, 256, 0, stream>>>(pstats, out);
}

// Round 2
// 122.730 us; speedup vs baseline: 2.2215x; 2.2215x over previous
//
#include <hip/hip_runtime.h>
#include <stdint.h>

#define N_ROWS 8192
#define D_DIM  1024
#define NEG_BIG -1e30f
#define NCHUNK 8
#define CHUNK_J 1024
#define NTILE 32            // 32 j-cols per tile, 32 tiles per chunk
#define PITCH 1040          // 1024B row + 16B skew -> even bank use, 16B-aligned rows
#define BUFSZ (32 * PITCH)  // 33280 B per buffer

typedef __attribute__((ext_vector_type(16))) float f32x16;

// branchless insert of v into descending sorted 5-list b0..b4
#define INS5(b0,b1,b2,b3,b4,v) {                    \
    float _x0 = fminf(b0,(v)); b0 = fmaxf(b0,(v));  \
    float _x1 = fminf(b1,_x0); b1 = fmaxf(b1,_x0);  \
    float _x2 = fminf(b2,_x1); b2 = fmaxf(b2,_x1);  \
    float _x3 = fminf(b3,_x2); b3 = fmaxf(b3,_x2);  \
    b4 = fmaxf(b4,_x3); }

// f32 -> OCP e4m3fn, RNE, with denormals. |x| <= 1 here (normalized rows).
static __device__ inline uint32_t f2e4m3(float x) {
    uint32_t u = __float_as_uint(x);
    uint32_t s = (u >> 24) & 0x80u;
    uint32_t a = u & 0x7fffffffu;
    uint32_t e = a >> 23;               // biased f32 exponent
    uint32_t out;
    if (e >= 121u) {                    // |x| >= 2^-6: normal e4m3
        uint32_t mant = a & 0x7fffffu;
        uint32_t comb = ((e - 120u) << 3) | (mant >> 20);
        uint32_t rem  = mant & 0xfffffu;
        comb += (rem > 0x80000u) || ((rem == 0x80000u) && (comb & 1u));
        out = comb;                     // mantissa carry into exponent is correct
    } else {                            // subnormal: round(|x| * 512) in [0,8]; 8 encodes 2^-6
        float scl = __uint_as_float(a) * 512.0f;
        out = (uint32_t)(int)rintf(scl);
    }
    return s | out;
}

// ---------------- K1: row-normalize f32 -> fp8 e4m3 ----------------
__global__ __launch_bounds__(256) void norm_kernel(const float* __restrict__ z,
                                                   uint8_t* __restrict__ zn8) {
    int wave = threadIdx.x >> 6;
    int lane = threadIdx.x & 63;
    int row  = blockIdx.x * 4 + wave;
    const float* zr = z + (size_t)row * D_DIM;
    float4 c[4];
    float ss = 0.f;
#pragma unroll
    for (int i = 0; i < 4; ++i) {
        c[i] = *(const float4*)(zr + i * 256 + lane * 4);
        ss += c[i].x*c[i].x + c[i].y*c[i].y + c[i].z*c[i].z + c[i].w*c[i].w;
    }
#pragma unroll
    for (int m = 1; m < 64; m <<= 1) ss += __shfl_xor(ss, m);
    float scale = 1.0f / fmaxf(sqrtf(ss), 1e-12f);
    uint8_t* zo = zn8 + (size_t)row * D_DIM;
#pragma unroll
    for (int i = 0; i < 4; ++i) {
        uint32_t d = f2e4m3(c[i].x * scale)
                   | (f2e4m3(c[i].y * scale) << 8)
                   | (f2e4m3(c[i].z * scale) << 16)
                   | (f2e4m3(c[i].w * scale) << 24);
        *(uint32_t*)(zo + i * 256 + lane * 4) = d;
    }
}

// ---------------- K2: fused fp8 sim + fixed-max sum + top5 partials ----------------
// grid: 64 i-blocks (128 rows, 32/wave) x 8 j-chunks (1024 cols).
// MFMA swapped: A = streamed j-tile (LDS), B = resident i-rows (128 VGPRs).
// D[j', i']: per-lane col = i (one output row per lane) -> 7 stats regs.
__global__ __launch_bounds__(256, 2) void sim_kernel(const uint8_t* __restrict__ zn8,
                                                     float* __restrict__ pstats) {
    __shared__ __align__(16) char lds[2 * BUFSZ];
    const int tid  = threadIdx.x;
    const int w    = tid >> 6;
    const int l    = tid & 63;
    const int r32  = l & 31;
    const int h    = l >> 5;
    const int ib   = blockIdx.x >> 3;
    const int ch   = blockIdx.x & 7;
    const int i0w  = ib * 128 + w * 32;
    const int j0c  = ch * CHUNK_J;
    const int i_lane = i0w + r32;
    const int diag_jt = (ch == (ib >> 3)) ? ((ib & 7) * 4 + w) : -1;

    // prologue: stage tile 0 into buffer 0 (rows w*8+u; linear dest, 1 row per instr)
#pragma unroll
    for (int u = 0; u < 8; ++u) {
        int jr = w * 8 + u;
        const uint8_t* src = zn8 + (size_t)(j0c + jr) * D_DIM + l * 16;
        char* dst = lds + jr * PITCH;
        __builtin_amdgcn_global_load_lds(
            (const __attribute__((address_space(1))) uint32_t*)src,
            (__attribute__((address_space(3))) uint32_t*)dst, 16, 0, 0);
    }

    // resident B-operand: lane l holds col i0w+r32, k = kk*16 + h*8 .. +7
    long bres[64];
    {
        const uint8_t* rp = zn8 + (size_t)i_lane * D_DIM + h * 8;
#pragma unroll
        for (int kk = 0; kk < 64; ++kk)
            bres[kk] = *(const long*)(rp + kk * 16);
    }

    float s_run = 0.f;
    float b0 = NEG_BIG, b1 = NEG_BIG, b2 = NEG_BIG, b3 = NEG_BIG, b4 = NEG_BIG;
    const int lbase = r32 * PITCH + h * 8;

    __syncthreads();

    for (int jt = 0; jt < NTILE; ++jt) {
        const int cur = jt & 1;
        if (jt + 1 < NTILE) {               // stage next tile into other buffer
            const int jb = j0c + (jt + 1) * 32;
            char* bufn = lds + (cur ^ 1) * BUFSZ;
#pragma unroll
            for (int u = 0; u < 8; ++u) {
                int jr = w * 8 + u;
                const uint8_t* src = zn8 + (size_t)(jb + jr) * D_DIM + l * 16;
                char* dst = bufn + jr * PITCH;
                __builtin_amdgcn_global_load_lds(
                    (const __attribute__((address_space(1))) uint32_t*)src,
                    (__attribute__((address_space(3))) uint32_t*)dst, 16, 0, 0);
            }
        }
        const char* bufp = lds + cur * BUFSZ + lbase;
        f32x16 acc0, acc1;
#pragma unroll
        for (int r = 0; r < 16; ++r) { acc0[r] = 0.f; acc1[r] = 0.f; }
#pragma unroll
        for (int kk = 0; kk < 64; kk += 2) {   // 2 independent acc chains
            long a0 = *(const long*)(bufp + kk * 16);
            long a1 = *(const long*)(bufp + kk * 16 + 16);
            acc0 = __builtin_amdgcn_mfma_f32_32x32x16_fp8_fp8(a0, bres[kk],     acc0, 0, 0, 0);
            acc1 = __builtin_amdgcn_mfma_f32_32x32x16_fp8_fp8(a1, bres[kk + 1], acc1, 0, 0, 0);
        }
        // epilogue: fixed max m=10 -> s += exp(10*sim - 10); top5 insert
        if (jt != diag_jt) {
#pragma unroll
            for (int r = 0; r < 16; ++r) {
                float v = acc0[r] + acc1[r];
                INS5(b0, b1, b2, b3, b4, v);
                s_run += __expf(fmaf(v, 10.f, -10.f));
            }
        } else {
            const int dd2 = i_lane - (j0c + jt * 32) - 4 * h;
#pragma unroll
            for (int r = 0; r < 16; ++r) {
                const int jm = (r & 3) + 8 * (r >> 2);
                float v = acc0[r] + acc1[r];
                if (dd2 == jm) v = NEG_BIG;    // exclude diagonal
                INS5(b0, b1, b2, b3, b4, v);
                s_run += __expf(fmaf(v, 10.f, -10.f));
            }
        }
        __syncthreads();                       // staging done + readers done
    }

    // merge the two h-halves: lanes l and l^32 hold the same output row
    s_run += __shfl_xor(s_run, 32);
    {
        float o0 = __shfl_xor(b0, 32), o1 = __shfl_xor(b1, 32), o2 = __shfl_xor(b2, 32),
              o3 = __shfl_xor(b3, 32), o4 = __shfl_xor(b4, 32);
        INS5(b0, b1, b2, b3, b4, o0); INS5(b0, b1, b2, b3, b4, o1);
        INS5(b0, b1, b2, b3, b4, o2); INS5(b0, b1, b2, b3, b4, o3);
        INS5(b0, b1, b2, b3, b4, o4);
    }
    if (h == 0) {
        float* p = pstats + ((size_t)ch * N_ROWS + i_lane) * 8;
        p[0] = s_run; p[1] = b0; p[2] = b1; p[3] = b2; p[4] = b3; p[5] = b4;
        p[6] = 0.f; p[7] = 0.f;
    }
}

// ---------------- K3: per-row merge of 8 chunk partials ----------------
__global__ __launch_bounds__(128) void reduce1(const float* __restrict__ pstats,
                                               float* __restrict__ partial) {
    int row = blockIdx.x * 128 + threadIdx.x;
    float S = 0.f;
    float b0 = NEG_BIG, b1 = NEG_BIG, b2 = NEG_BIG, b3 = NEG_BIG, b4 = NEG_BIG;
#pragma unroll
    for (int c = 0; c < NCHUNK; ++c) {
        const float* p = pstats + ((size_t)c * N_ROWS + row) * 8;
        S += p[0];
        float v0 = p[1], v1 = p[2], v2 = p[3], v3 = p[4], v4 = p[5];
        INS5(b0, b1, b2, b3, b4, v0); INS5(b0, b1, b2, b3, b4, v1);
        INS5(b0, b1, b2, b3, b4, v2); INS5(b0, b1, b2, b3, b4, v3);
        INS5(b0, b1, b2, b3, b4, v4);
    }
    float S5 = __expf(fmaf(b0, 10.f, -10.f)) + __expf(fmaf(b1, 10.f, -10.f))
             + __expf(fmaf(b2, 10.f, -10.f)) + __expf(fmaf(b3, 10.f, -10.f))
             + __expf(fmaf(b4, 10.f, -10.f));
    float loss = __logf(S) - __logf(S5);
#pragma unroll
    for (int m = 1; m < 64; m <<= 1) loss += __shfl_xor(loss, m);
    __shared__ float rr[2];
    if ((threadIdx.x & 63) == 0) rr[threadIdx.x >> 6] = loss;
    __syncthreads();
    if (threadIdx.x == 0) partial[blockIdx.x] = rr[0] + rr[1];
}

// ---------------- K4: final mean ----------------
__global__ void reduce2(const float* __restrict__ partial, float* __restrict__ out) {
    float v = partial[threadIdx.x];   // 64 partials
#pragma unroll
    for (int m = 1; m < 64; m <<= 1) v += __shfl_xor(v, m);
    if (threadIdx.x == 0) out[0] = v * (1.0f / N_ROWS);
}

extern "C" void kernel_launch(void* const* d_in, const int* in_sizes, int n_in,
                              void* d_out, int out_size, void* d_ws, size_t ws_size,
                              hipStream_t stream) {
    const float* z = (const float*)d_in[0];
    float* out = (float*)d_out;
    uint8_t* zn8   = (uint8_t*)d_ws;                                   // 8 MB
    float* pstats  = (float*)((char*)d_ws + (size_t)8 * 1024 * 1024);  // 2 MB
    float* partial = (float*)((char*)d_ws + (size_t)10 * 1024 * 1024); // 256 B

    norm_kernel<<<N_ROWS / 4, 256, 0, stream>>>(z, zn8);
    sim_kernel<<<64 * NCHUNK, 256, 0, stream>>>(zn8, pstats);
    reduce1<<<N_ROWS / 128, 128, 0, stream>>>(pstats, partial);
    reduce2<<<1, 64, 0, stream>>>(partial, out);
}

// Round 3
// 115.345 us; speedup vs baseline: 2.3637x; 1.0640x over previous
//
#include <hip/hip_runtime.h>
#include <stdint.h>

#define N_ROWS 8192
#define D_DIM  1024
#define NEG_BIG -1e30f
#define NCHUNK 8
#define CHUNK_J 1024
#define NTILE 32            // 32 j-cols per tile, 32 tiles per chunk
#define BUFSZ (32 * 1024)   // 32 rows x 1024 B, swizzled layout

typedef __attribute__((ext_vector_type(16))) float f32x16;
typedef __attribute__((ext_vector_type(2)))  long long2_t;

// log2(e) * 10 : exp(10v - 10) = exp2(v*C - C)
#define EXPC 14.4269504089f
#define EXPV(v) exp2f(fmaf((v), EXPC, -EXPC))

// branchless sorted insert of v into descending 5-list, med3 form (5 ops)
#define INS5(b0,b1,b2,b3,b4,v) {                        \
    float _n4 = __builtin_amdgcn_fmed3f(b3, (v), b4);   \
    float _n3 = __builtin_amdgcn_fmed3f(b2, (v), b3);   \
    float _n2 = __builtin_amdgcn_fmed3f(b1, (v), b2);   \
    float _n1 = __builtin_amdgcn_fmed3f(b0, (v), b1);   \
    b0 = fmaxf(b0, (v)); b1 = _n1; b2 = _n2; b3 = _n3; b4 = _n4; }

// f32 -> OCP e4m3fn, RNE, with denormals. |x| <= ~1 here (normalized rows).
static __device__ inline uint32_t f2e4m3(float x) {
    uint32_t u = __float_as_uint(x);
    uint32_t s = (u >> 24) & 0x80u;
    uint32_t a = u & 0x7fffffffu;
    uint32_t e = a >> 23;
    uint32_t out;
    if (e >= 121u) {
        uint32_t mant = a & 0x7fffffu;
        uint32_t comb = ((e - 120u) << 3) | (mant >> 20);
        uint32_t rem  = mant & 0xfffffu;
        comb += (rem > 0x80000u) || ((rem == 0x80000u) && (comb & 1u));
        out = comb;
    } else {
        float scl = __uint_as_float(a) * 512.0f;
        out = (uint32_t)(int)rintf(scl);
    }
    return s | out;
}

// ---------------- K1: row-normalize f32 -> fp8 e4m3 ----------------
__global__ __launch_bounds__(256) void norm_kernel(const float* __restrict__ z,
                                                   uint8_t* __restrict__ zn8) {
    int wave = threadIdx.x >> 6;
    int lane = threadIdx.x & 63;
    int row  = blockIdx.x * 4 + wave;
    const float* zr = z + (size_t)row * D_DIM;
    float4 c[4];
    float ss = 0.f;
#pragma unroll
    for (int i = 0; i < 4; ++i) {
        c[i] = *(const float4*)(zr + i * 256 + lane * 4);
        ss += c[i].x*c[i].x + c[i].y*c[i].y + c[i].z*c[i].z + c[i].w*c[i].w;
    }
#pragma unroll
    for (int m = 1; m < 64; m <<= 1) ss += __shfl_xor(ss, m);
    float scale = 1.0f / fmaxf(sqrtf(ss), 1e-12f);
    uint8_t* zo = zn8 + (size_t)row * D_DIM;
#pragma unroll
    for (int i = 0; i < 4; ++i) {
        uint32_t d = f2e4m3(c[i].x * scale)
                   | (f2e4m3(c[i].y * scale) << 8)
                   | (f2e4m3(c[i].z * scale) << 16)
                   | (f2e4m3(c[i].w * scale) << 24);
        *(uint32_t*)(zo + i * 256 + lane * 4) = d;
    }
}

// ---------------- K2: fused fp8 sim + fixed-max sum + top5 partials ----------------
// grid: 64 i-blocks (128 rows, 32/wave) x 8 j-chunks (1024 cols).
// Swapped MFMA: A = streamed j-tile (LDS, XOR-swizzled, b128 reads),
// B = resident i-rows pinned in 128 VGPRs. Lane owns one output row.
// k-permutation: MFMA 2t covers k[32t,32t+8)+k[32t+16,32t+24) (h-halves),
// MFMA 2t+1 the complements; A and B use the same permutation.
__global__ __launch_bounds__(256, 2) void sim_kernel(const uint8_t* __restrict__ zn8,
                                                     float* __restrict__ pstats) {
    __shared__ __align__(16) char lds[2 * BUFSZ];
    const int tid  = threadIdx.x;
    const int w    = tid >> 6;
    const int l    = tid & 63;
    const int r32  = l & 31;
    const int h    = l >> 5;
    const int ib   = blockIdx.x >> 3;
    const int ch   = blockIdx.x & 7;
    const int i0w  = ib * 128 + w * 32;
    const int j0c  = ch * CHUNK_J;
    const int i_lane = i0w + r32;
    const int diag_jt = (ch == (ib >> 3)) ? ((ib & 7) * 4 + w) : -1;
    const int swz2 = (((l & 7) ^ h) << 4);   // read-side XOR (bits 4-6)

    // prologue: stage tile 0 into buffer 0 (linear LDS dest, pre-swizzled source)
#pragma unroll
    for (int u = 0; u < 8; ++u) {
        int jr = w * 8 + u;
        const uint8_t* src = zn8 + (size_t)(j0c + jr) * D_DIM + ((l ^ u) << 4);
        char* dst = lds + jr * 1024;
        __builtin_amdgcn_global_load_lds(
            (const __attribute__((address_space(1))) uint32_t*)src,
            (__attribute__((address_space(3))) uint32_t*)dst, 16, 0, 0);
    }

    // resident B-operand: lane holds col i_lane; bres[2t],bres[2t+1] per k-perm
    long bres[64];
    {
        const uint8_t* rp = zn8 + (size_t)i_lane * D_DIM + h * 16;
#pragma unroll
        for (int t = 0; t < 32; ++t) {
            long2_t m = *(const long2_t*)(rp + t * 32);
            bres[2 * t]     = m[0];
            bres[2 * t + 1] = m[1];
        }
    }
#pragma unroll
    for (int t = 0; t < 64; ++t)
        asm volatile("" : "+v"(bres[t]));   // pin resident: forbid remat/reload

    float s0r = 0.f, s1r = 0.f;
    float b0 = NEG_BIG, b1 = NEG_BIG, b2 = NEG_BIG, b3 = NEG_BIG, b4 = NEG_BIG;
    const char* bA = lds + r32 * 1024;
    const char* bB = lds + BUFSZ + r32 * 1024;

    __syncthreads();

    for (int jt = 0; jt < NTILE; ++jt) {
        if (jt + 1 < NTILE) {               // stage next tile into other buffer
            const int jb = j0c + (jt + 1) * 32;
            char* bufn = lds + ((jt & 1) ^ 1) * BUFSZ;
#pragma unroll
            for (int u = 0; u < 8; ++u) {
                int jr = w * 8 + u;
                const uint8_t* src = zn8 + (size_t)(jb + jr) * D_DIM + ((l ^ u) << 4);
                char* dst = bufn + jr * 1024;
                __builtin_amdgcn_global_load_lds(
                    (const __attribute__((address_space(1))) uint32_t*)src,
                    (__attribute__((address_space(3))) uint32_t*)dst, 16, 0, 0);
            }
        }
        const char* bc = (jt & 1) ? bB : bA;
        const char* q0 = bc + (0  ^ swz2);
        const char* q1 = bc + (32 ^ swz2);
        const char* q2 = bc + (64 ^ swz2);
        const char* q3 = bc + (96 ^ swz2);

        f32x16 acc0, acc1;
#pragma unroll
        for (int r = 0; r < 16; ++r) { acc0[r] = 0.f; acc1[r] = 0.f; }
#pragma unroll
        for (int tt = 0; tt < 8; ++tt) {
            long2_t m0 = *(const long2_t*)(q0 + tt * 128);
            long2_t m1 = *(const long2_t*)(q1 + tt * 128);
            long2_t m2 = *(const long2_t*)(q2 + tt * 128);
            long2_t m3 = *(const long2_t*)(q3 + tt * 128);
            acc0 = __builtin_amdgcn_mfma_f32_32x32x16_fp8_fp8(m0[0], bres[tt * 8 + 0], acc0, 0, 0, 0);
            acc1 = __builtin_amdgcn_mfma_f32_32x32x16_fp8_fp8(m0[1], bres[tt * 8 + 1], acc1, 0, 0, 0);
            acc0 = __builtin_amdgcn_mfma_f32_32x32x16_fp8_fp8(m1[0], bres[tt * 8 + 2], acc0, 0, 0, 0);
            acc1 = __builtin_amdgcn_mfma_f32_32x32x16_fp8_fp8(m1[1], bres[tt * 8 + 3], acc1, 0, 0, 0);
            acc0 = __builtin_amdgcn_mfma_f32_32x32x16_fp8_fp8(m2[0], bres[tt * 8 + 4], acc0, 0, 0, 0);
            acc1 = __builtin_amdgcn_mfma_f32_32x32x16_fp8_fp8(m2[1], bres[tt * 8 + 5], acc1, 0, 0, 0);
            acc0 = __builtin_amdgcn_mfma_f32_32x32x16_fp8_fp8(m3[0], bres[tt * 8 + 6], acc0, 0, 0, 0);
            acc1 = __builtin_amdgcn_mfma_f32_32x32x16_fp8_fp8(m3[1], bres[tt * 8 + 7], acc1, 0, 0, 0);
        }

        // epilogue: fixed max m=10 -> s += exp2(C*v - C); med3 top5 insert
        if (jt != diag_jt) {
#pragma unroll
            for (int r = 0; r < 16; ++r) {
                float v = acc0[r] + acc1[r];
                INS5(b0, b1, b2, b3, b4, v);
                if (r & 1) s1r += EXPV(v); else s0r += EXPV(v);
            }
        } else {
            const int dd2 = i_lane - (j0c + jt * 32) - 4 * h;
#pragma unroll
            for (int r = 0; r < 16; ++r) {
                const int jm = (r & 3) + 8 * (r >> 2);
                float v = acc0[r] + acc1[r];
                if (dd2 == jm) v = NEG_BIG;    // exclude diagonal
                INS5(b0, b1, b2, b3, b4, v);
                if (r & 1) s1r += EXPV(v); else s0r += EXPV(v);
            }
        }
        __syncthreads();                       // staging done + readers done
    }

    float s_run = s0r + s1r;
    // merge the two h-halves: lanes l and l^32 hold the same output row
    s_run += __shfl_xor(s_run, 32);
    {
        float o0 = __shfl_xor(b0, 32), o1 = __shfl_xor(b1, 32), o2 = __shfl_xor(b2, 32),
              o3 = __shfl_xor(b3, 32), o4 = __shfl_xor(b4, 32);
        INS5(b0, b1, b2, b3, b4, o0); INS5(b0, b1, b2, b3, b4, o1);
        INS5(b0, b1, b2, b3, b4, o2); INS5(b0, b1, b2, b3, b4, o3);
        INS5(b0, b1, b2, b3, b4, o4);
    }
    if (h == 0) {
        float* p = pstats + ((size_t)ch * N_ROWS + i_lane) * 8;
        p[0] = s_run; p[1] = b0; p[2] = b1; p[3] = b2; p[4] = b3; p[5] = b4;
        p[6] = 0.f; p[7] = 0.f;
    }
}

// ---------------- K3: per-row merge of 8 chunk partials ----------------
__global__ __launch_bounds__(128) void reduce1(const float* __restrict__ pstats,
                                               float* __restrict__ partial) {
    int row = blockIdx.x * 128 + threadIdx.x;
    float S = 0.f;
    float b0 = NEG_BIG, b1 = NEG_BIG, b2 = NEG_BIG, b3 = NEG_BIG, b4 = NEG_BIG;
#pragma unroll
    for (int c = 0; c < NCHUNK; ++c) {
        const float* p = pstats + ((size_t)c * N_ROWS + row) * 8;
        S += p[0];
        float v0 = p[1], v1 = p[2], v2 = p[3], v3 = p[4], v4 = p[5];
        INS5(b0, b1, b2, b3, b4, v0); INS5(b0, b1, b2, b3, b4, v1);
        INS5(b0, b1, b2, b3, b4, v2); INS5(b0, b1, b2, b3, b4, v3);
        INS5(b0, b1, b2, b3, b4, v4);
    }
    float S5 = EXPV(b0) + EXPV(b1) + EXPV(b2) + EXPV(b3) + EXPV(b4);
    float loss = __logf(S) - __logf(S5);
#pragma unroll
    for (int m = 1; m < 64; m <<= 1) loss += __shfl_xor(loss, m);
    __shared__ float rr[2];
    if ((threadIdx.x & 63) == 0) rr[threadIdx.x >> 6] = loss;
    __syncthreads();
    if (threadIdx.x == 0) partial[blockIdx.x] = rr[0] + rr[1];
}

// ---------------- K4: final mean ----------------
__global__ void reduce2(const float* __restrict__ partial, float* __restrict__ out) {
    float v = partial[threadIdx.x];   // 64 partials
#pragma unroll
    for (int m = 1; m < 64; m <<= 1) v += __shfl_xor(v, m);
    if (threadIdx.x == 0) out[0] = v * (1.0f / N_ROWS);
}

extern "C" void kernel_launch(void* const* d_in, const int* in_sizes, int n_in,
                              void* d_out, int out_size, void* d_ws, size_t ws_size,
                              hipStream_t stream) {
    const float* z = (const float*)d_in[0];
    float* out = (float*)d_out;
    uint8_t* zn8   = (uint8_t*)d_ws;                                   // 8 MB
    float* pstats  = (float*)((char*)d_ws + (size_t)8 * 1024 * 1024);  // 2 MB
    float* partial = (float*)((char*)d_ws + (size_t)10 * 1024 * 1024); // 256 B

    norm_kernel<<<N_ROWS / 4, 256, 0, stream>>>(z, zn8);
    sim_kernel<<<64 * NCHUNK, 256, 0, stream>>>(zn8, pstats);
    reduce1<<<N_ROWS / 128, 128, 0, stream>>>(pstats, partial);
    reduce2<<<1, 64, 0, stream>>>(partial, out);
}

// Round 4
// 96.150 us; speedup vs baseline: 2.8356x; 1.1996x over previous
//
#include <hip/hip_runtime.h>
#include <stdint.h>

#define N_ROWS 8192
#define D_DIM  1024
#define NEG_BIG -1e30f
#define NCHUNK 8
#define CHUNK_J 1024
#define NTILE 32            // 32 j-cols per tile, 32 tiles per chunk
#define BUFSZ (32 * 1024)   // 32 rows x 1024 B, swizzled (32B-granule XOR) layout

typedef __attribute__((ext_vector_type(16))) float f32x16;
typedef __attribute__((ext_vector_type(8)))  int   i32x8;
typedef __attribute__((ext_vector_type(2)))  long  long2_t;

// log2(e) * 10 : exp(10v - 10) = exp2(v*C - C)
#define EXPC 14.4269504089f
#define EXPV(v) exp2f(fmaf((v), EXPC, -EXPC))

// branchless sorted insert of v into descending 5-list, med3 form (5 ops)
#define INS5(b0,b1,b2,b3,b4,v) {                        \
    float _n4 = __builtin_amdgcn_fmed3f(b3, (v), b4);   \
    float _n3 = __builtin_amdgcn_fmed3f(b2, (v), b3);   \
    float _n2 = __builtin_amdgcn_fmed3f(b1, (v), b2);   \
    float _n1 = __builtin_amdgcn_fmed3f(b0, (v), b1);   \
    b0 = fmaxf(b0, (v)); b1 = _n1; b2 = _n2; b3 = _n3; b4 = _n4; }

// f32 -> OCP e4m3fn, RNE, with denormals. |x| <= ~1 here (normalized rows).
static __device__ inline uint32_t f2e4m3(float x) {
    uint32_t u = __float_as_uint(x);
    uint32_t s = (u >> 24) & 0x80u;
    uint32_t a = u & 0x7fffffffu;
    uint32_t e = a >> 23;
    uint32_t out;
    if (e >= 121u) {
        uint32_t mant = a & 0x7fffffu;
        uint32_t comb = ((e - 120u) << 3) | (mant >> 20);
        uint32_t rem  = mant & 0xfffffu;
        comb += (rem > 0x80000u) || ((rem == 0x80000u) && (comb & 1u));
        out = comb;
    } else {
        float scl = __uint_as_float(a) * 512.0f;
        out = (uint32_t)(int)rintf(scl);
    }
    return s | out;
}

// ---------------- K1: row-normalize f32 -> fp8 e4m3 ----------------
__global__ __launch_bounds__(256) void norm_kernel(const float* __restrict__ z,
                                                   uint8_t* __restrict__ zn8) {
    int wave = threadIdx.x >> 6;
    int lane = threadIdx.x & 63;
    int row  = blockIdx.x * 4 + wave;
    const float* zr = z + (size_t)row * D_DIM;
    float4 c[4];
    float ss = 0.f;
#pragma unroll
    for (int i = 0; i < 4; ++i) {
        c[i] = *(const float4*)(zr + i * 256 + lane * 4);
        ss += c[i].x*c[i].x + c[i].y*c[i].y + c[i].z*c[i].z + c[i].w*c[i].w;
    }
#pragma unroll
    for (int m = 1; m < 64; m <<= 1) ss += __shfl_xor(ss, m);
    float scale = 1.0f / fmaxf(sqrtf(ss), 1e-12f);
    uint8_t* zo = zn8 + (size_t)row * D_DIM;
#pragma unroll
    for (int i = 0; i < 4; ++i) {
        uint32_t d = f2e4m3(c[i].x * scale)
                   | (f2e4m3(c[i].y * scale) << 8)
                   | (f2e4m3(c[i].z * scale) << 16)
                   | (f2e4m3(c[i].w * scale) << 24);
        *(uint32_t*)(zo + i * 256 + lane * 4) = d;
    }
}

// ---------------- K2: fused fp8 sim via scale-MFMA K=64 ----------------
// grid: 64 i-blocks (128 rows, 32/wave) x 8 j-chunks (1024 cols).
// Swapped MFMA: A = streamed j-tile (LDS), B = resident i-rows (truly pinned,
// 128 VGPRs). mfma_scale_f32_32x32x64_f8f6f4 with unit scales (E8M0 127).
// LDS store swizzle: 16B-slot l holds global slot l^(jr&6) (32B-granule XOR,
// preserves pair order). Reads: 16 persistent per-lane offsets, buffer toggle
// via 2x-unrolled loop -> all ds_read offsets are immediates.
__global__ __launch_bounds__(256, 2) void sim_kernel(const uint8_t* __restrict__ zn8,
                                                     float* __restrict__ pstats) {
    __shared__ __align__(16) char lds[2 * BUFSZ];
    const int tid  = threadIdx.x;
    const int w    = tid >> 6;
    const int l    = tid & 63;
    const int r32  = l & 31;
    const int h    = l >> 5;
    const int x6   = l & 6;
    const int ib   = blockIdx.x >> 3;
    const int ch   = blockIdx.x & 7;
    const int i0w  = ib * 128 + w * 32;
    const int j0c  = ch * CHUNK_J;
    const int i_lane = i0w + r32;
    const int diag_jt = (ch == (ib >> 3)) ? ((ib & 7) * 4 + w) : -1;

    // persistent per-lane LDS read offsets: MFMA m needs global 16B-slots
    // {4m+2h, 4m+2h+1} of row r32 -> LDS slot (4m+2h)^x6, pair stays ordered.
    int roff[16];
#pragma unroll
    for (int m = 0; m < 16; ++m)
        roff[m] = r32 * 1024 + (((4 * m + 2 * h) ^ x6) << 4);

    // prologue: stage tile 0 into buffer 0
#pragma unroll
    for (int u = 0; u < 8; ++u) {
        int jr = w * 8 + u;
        const uint8_t* src = zn8 + (size_t)(j0c + jr) * D_DIM + ((l ^ (jr & 6)) << 4);
        char* dst = lds + jr * 1024;
        __builtin_amdgcn_global_load_lds(
            (const __attribute__((address_space(1))) uint32_t*)src,
            (__attribute__((address_space(3))) uint32_t*)dst, 16, 0, 0);
    }

    // resident B-operand: lane holds col i_lane; bres[m] = k bytes [m*64+h*32, +32)
    i32x8 bres[16];
    {
        const uint8_t* rp = zn8 + (size_t)i_lane * D_DIM + h * 32;
#pragma unroll
        for (int m = 0; m < 16; ++m) {
            *(long2_t*)&bres[m]       = *(const long2_t*)(rp + m * 64);
            *((long2_t*)&bres[m] + 1) = *(const long2_t*)(rp + m * 64 + 16);
        }
    }

    float s0r = 0.f, s1r = 0.f;
    float b0 = NEG_BIG, b1 = NEG_BIG, b2 = NEG_BIG, b3 = NEG_BIG, b4 = NEG_BIG;

    __syncthreads();

#define TILE_BODY(JT, CUR) {                                                    \
        if ((JT) + 1 < NTILE) {                                                 \
            const int jb_ = j0c + ((JT) + 1) * 32;                              \
            char* bufn_ = lds + ((CUR) ^ BUFSZ);                                \
            _Pragma("unroll")                                                   \
            for (int u = 0; u < 8; ++u) {                                       \
                int jr = w * 8 + u;                                             \
                const uint8_t* src = zn8 + (size_t)(jb_ + jr) * D_DIM           \
                                     + ((l ^ (jr & 6)) << 4);                   \
                char* dst = bufn_ + jr * 1024;                                  \
                __builtin_amdgcn_global_load_lds(                               \
                    (const __attribute__((address_space(1))) uint32_t*)src,     \
                    (__attribute__((address_space(3))) uint32_t*)dst, 16, 0, 0);\
            }                                                                   \
        }                                                                       \
        f32x16 acc0, acc1;                                                      \
        _Pragma("unroll")                                                       \
        for (int r = 0; r < 16; ++r) { acc0[r] = 0.f; acc1[r] = 0.f; }          \
        __builtin_amdgcn_s_setprio(1);                                          \
        _Pragma("unroll")                                                       \
        for (int m = 0; m < 16; ++m) {                                          \
            asm volatile("" : "+v"(bres[m]));  /* true residency */             \
            i32x8 a;                                                            \
            *(long2_t*)&a       = *(const long2_t*)(lds + (CUR) + roff[m]);     \
            *((long2_t*)&a + 1) = *(const long2_t*)(lds + (CUR) + roff[m] + 16);\
            if (m & 1)                                                          \
                acc1 = __builtin_amdgcn_mfma_scale_f32_32x32x64_f8f6f4(         \
                    a, bres[m], acc1, 0, 0, 0, 127, 0, 127);                    \
            else                                                                \
                acc0 = __builtin_amdgcn_mfma_scale_f32_32x32x64_f8f6f4(         \
                    a, bres[m], acc0, 0, 0, 0, 127, 0, 127);                    \
        }                                                                       \
        __builtin_amdgcn_s_setprio(0);                                          \
        if ((JT) != diag_jt) {                                                  \
            _Pragma("unroll")                                                   \
            for (int r = 0; r < 16; ++r) {                                      \
                float v = acc0[r] + acc1[r];                                    \
                INS5(b0, b1, b2, b3, b4, v);                                    \
                if (r & 1) s1r += EXPV(v); else s0r += EXPV(v);                 \
            }                                                                   \
        } else {                                                                \
            const int dd2 = i_lane - (j0c + (JT) * 32) - 4 * h;                 \
            _Pragma("unroll")                                                   \
            for (int r = 0; r < 16; ++r) {                                      \
                const int jm = (r & 3) + 8 * (r >> 2);                          \
                float v = acc0[r] + acc1[r];                                    \
                if (dd2 == jm) v = NEG_BIG;                                     \
                INS5(b0, b1, b2, b3, b4, v);                                    \
                if (r & 1) s1r += EXPV(v); else s0r += EXPV(v);                 \
            }                                                                   \
        }                                                                       \
        __syncthreads();                                                        \
    }

    for (int jt = 0; jt < NTILE; jt += 2) {
        TILE_BODY(jt, 0);
        TILE_BODY(jt + 1, BUFSZ);
    }
#undef TILE_BODY

    float s_run = s0r + s1r;
    // merge the two h-halves: lanes l and l^32 hold complementary j-rows of col i
    s_run += __shfl_xor(s_run, 32);
    {
        float o0 = __shfl_xor(b0, 32), o1 = __shfl_xor(b1, 32), o2 = __shfl_xor(b2, 32),
              o3 = __shfl_xor(b3, 32), o4 = __shfl_xor(b4, 32);
        INS5(b0, b1, b2, b3, b4, o0); INS5(b0, b1, b2, b3, b4, o1);
        INS5(b0, b1, b2, b3, b4, o2); INS5(b0, b1, b2, b3, b4, o3);
        INS5(b0, b1, b2, b3, b4, o4);
    }
    if (h == 0) {
        float* p = pstats + ((size_t)ch * N_ROWS + i_lane) * 8;
        p[0] = s_run; p[1] = b0; p[2] = b1; p[3] = b2; p[4] = b3; p[5] = b4;
        p[6] = 0.f; p[7] = 0.f;
    }
}

// ---------------- K3: per-row merge of 8 chunk partials ----------------
__global__ __launch_bounds__(128) void reduce1(const float* __restrict__ pstats,
                                               float* __restrict__ partial) {
    int row = blockIdx.x * 128 + threadIdx.x;
    float S = 0.f;
    float b0 = NEG_BIG, b1 = NEG_BIG, b2 = NEG_BIG, b3 = NEG_BIG, b4 = NEG_BIG;
#pragma unroll
    for (int c = 0; c < NCHUNK; ++c) {
        const float* p = pstats + ((size_t)c * N_ROWS + row) * 8;
        S += p[0];
        float v0 = p[1], v1 = p[2], v2 = p[3], v3 = p[4], v4 = p[5];
        INS5(b0, b1, b2, b3, b4, v0); INS5(b0, b1, b2, b3, b4, v1);
        INS5(b0, b1, b2, b3, b4, v2); INS5(b0, b1, b2, b3, b4, v3);
        INS5(b0, b1, b2, b3, b4, v4);
    }
    float S5 = EXPV(b0) + EXPV(b1) + EXPV(b2) + EXPV(b3) + EXPV(b4);
    float loss = __logf(S) - __logf(S5);
#pragma unroll
    for (int m = 1; m < 64; m <<= 1) loss += __shfl_xor(loss, m);
    __shared__ float rr[2];
    if ((threadIdx.x & 63) == 0) rr[threadIdx.x >> 6] = loss;
    __syncthreads();
    if (threadIdx.x == 0) partial[blockIdx.x] = rr[0] + rr[1];
}

// ---------------- K4: final mean ----------------
__global__ void reduce2(const float* __restrict__ partial, float* __restrict__ out) {
    float v = partial[threadIdx.x];   // 64 partials
#pragma unroll
    for (int m = 1; m < 64; m <<= 1) v += __shfl_xor(v, m);
    if (threadIdx.x == 0) out[0] = v * (1.0f / N_ROWS);
}

extern "C" void kernel_launch(void* const* d_in, const int* in_sizes, int n_in,
                              void* d_out, int out_size, void* d_ws, size_t ws_size,
                              hipStream_t stream) {
    const float* z = (const float*)d_in[0];
    float* out = (float*)d_out;
    uint8_t* zn8   = (uint8_t*)d_ws;                                   // 8 MB
    float* pstats  = (float*)((char*)d_ws + (size_t)8 * 1024 * 1024);  // 2 MB
    float* partial = (float*)((char*)d_ws + (size_t)10 * 1024 * 1024); // 256 B

    norm_kernel<<<N_ROWS / 4, 256, 0, stream>>>(z, zn8);
    sim_kernel<<<64 * NCHUNK, 256, 0, stream>>>(zn8, pstats);
    reduce1<<<N_ROWS / 128, 128, 0, stream>>>(pstats, partial);
    reduce2<<<1, 64, 0, stream>>>(partial, out);
}